// Round 5
// baseline (766.083 us; speedup 1.0000x reference)
//
#include <hip/hip_runtime.h>
#include <math.h>
#include <stdint.h>

// AIS estimator: N=1024 samples, B=128, DIM=DX=64, K=16 anneal steps, 3 leapfrog.
// Round 20: k_main occupancy. r19 (staged RNG, 616us) left k_main at 321us with
// VALUBusy 84% / Occupancy 21% -- latency-limited at 2 blocks/CU
// (__launch_bounds__(256,2)). VGPR=100 and LDS=16KB both permit 4 blocks/CU
// (VGPR cap 128 > 100, LDS 64KB < 160KB) -> bound (256,4) doubles resident
// waves to hide the MFMA-accumulate / leapfrog-fma / ds-swizzle chains.
// Everything else identical to r19:
//  - k_fused: block 0 = k_eig (r18); blocks 1..512 = RNG producer (exact
//    DRAW+SPLIT, packed f16hi|f16lo u32); blocks 513..520 = setup2.
//  - k_main: j<=nS loads staged draws (dwordx4 + v_perm); nS from ws_size.
//  - leapfrog via v_pk_fma_f32 (__builtin_elementwise_fma), IEEE-identical.
// All staged bits flow through identical expressions -> absmax 1.0 preserved.

#define WS_A     0
#define WS_MU    4096
#define WS_C     12288
#define WS_XSQ   20480
#define WS_AMU   20608
#define WS_F     28800
#define WS_WC    36992
#define WS_V     37120
#define WS_LAM   41216
#define WS_FZ    41280
#define WS_VF    49472
#define WS_SLW   53568
#define WS_TOTAL (WS_SLW + 131072)
#define WS_RNG   (WS_SLW + 131072)   // optional u32 region: 524288*16*nS

#define LOG2PI 1.8378770664093453f

typedef _Float16 half8_t __attribute__((ext_vector_type(8)));
typedef float f4_t __attribute__((ext_vector_type(4)));
typedef unsigned int uint4_t __attribute__((ext_vector_type(4)));

struct KParams {
  float beta[18];
  float dbeta[17];
  uint32_t fk0[16];
  uint32_t fk1[16];
};

__host__ __device__ static inline void threefry2x32(uint32_t ks0, uint32_t ks1,
                                                    uint32_t x0, uint32_t x1,
                                                    uint32_t& o0, uint32_t& o1) {
  uint32_t ks2 = ks0 ^ ks1 ^ 0x1BD11BDAu;
  x0 += ks0; x1 += ks1;
#define TFR(r) { x0 += x1; x1 = (x1 << (r)) | (x1 >> (32 - (r))); x1 ^= x0; }
  TFR(13) TFR(15) TFR(26) TFR(6)
  x0 += ks1; x1 += ks2 + 1u;
  TFR(17) TFR(29) TFR(16) TFR(24)
  x0 += ks2; x1 += ks0 + 2u;
  TFR(13) TFR(15) TFR(26) TFR(6)
  x0 += ks0; x1 += ks1 + 3u;
  TFR(17) TFR(29) TFR(16) TFR(24)
  x0 += ks1; x1 += ks2 + 4u;
  TFR(13) TFR(15) TFR(26) TFR(6)
  x0 += ks2; x1 += ks0 + 5u;
#undef TFR
  o0 = x0; o1 = x1;
}

__device__ __forceinline__ float u_from_bits(uint32_t bits) {
  const float LO = __uint_as_float(0xBF7FFFFFu);  // nextafter(-1,0) in f32
  float f = __uint_as_float((bits >> 9) | 0x3F800000u) - 1.0f;
  return fmaf(f, 2.0f, LO);
}

// XLA ErfInv32 (Giles); __logf variant validated r11-r14 (absmax = 1 bf16 ulp)
__device__ __forceinline__ float erfinv_f(float x) {
  float w = -__logf(fmaf(-x, x, 1.0f));
  float p;
  if (w < 5.0f) {
    w -= 2.5f;
    p = 2.81022636e-08f;
    p = fmaf(p, w, 3.43273939e-07f);
    p = fmaf(p, w, -3.5233877e-06f);
    p = fmaf(p, w, -4.39150654e-06f);
    p = fmaf(p, w, 0.00021858087f);
    p = fmaf(p, w, -0.00125372503f);
    p = fmaf(p, w, -0.00417768164f);
    p = fmaf(p, w, 0.246640727f);
    p = fmaf(p, w, 1.50140941f);
  } else {
    w = sqrtf(w) - 3.0f;
    p = -0.000200214257f;
    p = fmaf(p, w, 0.000100950558f);
    p = fmaf(p, w, 0.00134934322f);
    p = fmaf(p, w, -0.00367342844f);
    p = fmaf(p, w, 0.00573950773f);
    p = fmaf(p, w, -0.0076224613f);
    p = fmaf(p, w, 0.00943887047f);
    p = fmaf(p, w, 1.00167406f);
    p = fmaf(p, w, 2.83297682f);
  }
  return p * x;
}

// ---- setup1: A = Wdec Wdec^T ; mu[b][d] ; c[b][d] ; xsq[b]
__global__ void k_setup1(const float* __restrict__ x, const float* __restrict__ Wenc,
                         const float* __restrict__ Wdec, float* __restrict__ ws) {
  int t = blockIdx.x * 256 + threadIdx.x;
  if (t < 4096) {
    int i = t >> 6, j = t & 63;
    float s = 0;
    for (int e = 0; e < 64; ++e) s = fmaf(Wdec[i*64+e], Wdec[j*64+e], s);
    ws[WS_A + t] = s;
  } else if (t < 12288) {
    int u = t - 4096; int b = u >> 6, d = u & 63;
    float s = 0;
    for (int e = 0; e < 64; ++e) s = fmaf(x[b*64+e], Wenc[e*64+d], s);
    ws[WS_MU + u] = s;
  } else if (t < 20480) {
    int u = t - 12288; int b = u >> 6, d = u & 63;
    float s = 0;
    for (int e = 0; e < 64; ++e) s = fmaf(x[b*64+e], Wdec[d*64+e], s);
    ws[WS_C + u] = s;
  } else if (t < 20608) {
    int b = t - 20480;
    float s = 0;
    for (int e = 0; e < 64; ++e) s = fmaf(x[b*64+e], x[b*64+e], s);
    ws[WS_XSQ + b] = s;
  }
}

#define DRAW(PC, IDX)                                                        \
  { uint32_t o0, o1;                                                         \
    threefry2x32(k0, k1, 0u, base + (IDX), o0, o1);                          \
    PC = 1.41421356f * erfinv_f(u_from_bits(o0 ^ o1)); }

#define PACKD(DST, DD)                                                       \
  { _Float16 hh = (_Float16)(DD);                                            \
    _Float16 ll = (_Float16)((DD) - (float)hh);                              \
    DST = (uint32_t)__builtin_bit_cast(unsigned short, hh) |                 \
          ((uint32_t)__builtin_bit_cast(unsigned short, ll) << 16); }

// ---- k_fused: block 0 = k_eig (r18 version); blocks 1..nRng = RNG producer;
// blocks nRng+1..nRng+8 = setup2. All roles independent (no inter-block deps).
#define EP 65
__global__ __launch_bounds__(1024) void k_fused(float* __restrict__ ws, KParams P,
                                                int nRng, int nS) {
  const int blk = blockIdx.x;
  const int tid = threadIdx.x;
  if (blk == 0) {
    // ---- cyclic Jacobi, 4 sweeps x 63 rounds, pitch 65 (r18, bit-identical)
    __shared__ float Am[64 * EP];
    __shared__ float Vm[64 * EP];
    __shared__ float cs_c[32], cs_s[32];
    __shared__ int ppu[32], ppv[32];
    for (int i = tid; i < 4096; i += 1024) {
      int r = i >> 6, c = i & 63;
      Am[r*EP + c] = ws[WS_A + i];
      Vm[r*EP + c] = (r == c) ? 1.0f : 0.0f;
    }
    const int pA = tid & 31;
    int uA = (pA == 0) ? 0 : pA;
    int vA = (pA == 0) ? 63 : (63 - pA);
    const int pV0 = tid >> 6;
    int uV0 = (pV0 == 0) ? 0 : pV0;
    int vV0 = (pV0 == 0) ? 63 : (63 - pV0);
    const int pV1 = 16 + pV0;
    int uV1 = pV1;
    int vV1 = 63 - pV1;
    __syncthreads();
    for (int sweep = 0; sweep < 4; ++sweep) {
      for (int r = 0; r < 63; ++r) {
        if (tid < 32) {
          float app = Am[uA*(EP+1)], aqq = Am[vA*(EP+1)], apq = Am[uA*EP+vA];
          float c = 1.0f, s = 0.0f;
          if (fabsf(apq) > 1e-30f) {
            float tau = (aqq - app) / (2.0f * apq);
            float t = copysignf(1.0f / (fabsf(tau) + sqrtf(fmaf(tau, tau, 1.0f))), tau);
            c = 1.0f / sqrtf(fmaf(t, t, 1.0f));
            s = t * c;
          }
          ppu[tid] = uA; ppv[tid] = vA; cs_c[tid] = c; cs_s[tid] = s;
        }
        __syncthreads();
        {
          int i = tid >> 5;
          int ui = ppu[i], vi = ppv[i];
          const int uj = uA, vj = vA;
          float ci = cs_c[i], si = cs_s[i], cj = cs_c[pA], sj = cs_s[pA];
          float a = Am[ui*EP+uj], bb = Am[ui*EP+vj];
          float d = Am[vi*EP+uj], e  = Am[vi*EP+vj];
          float r0u = ci*a  - si*d;
          float r1u = fmaf(si, a,  ci*d);
          float r0v = ci*bb - si*e;
          float r1v = fmaf(si, bb, ci*e);
          Am[ui*EP+uj] = cj*r0u - sj*r0v;
          Am[ui*EP+vj] = fmaf(sj, r0u, cj*r0v);
          Am[vi*EP+uj] = cj*r1u - sj*r1v;
          Am[vi*EP+vj] = fmaf(sj, r1u, cj*r1v);
        }
        {
          const int k = tid & 63;
          {
            float c2 = cs_c[pV0], s2 = cs_s[pV0];
            float vu = Vm[k*EP+uV0], vv = Vm[k*EP+vV0];
            Vm[k*EP+uV0] = c2*vu - s2*vv;
            Vm[k*EP+vV0] = fmaf(s2, vu, c2*vv);
          }
          {
            float c2 = cs_c[pV1], s2 = cs_s[pV1];
            float vu = Vm[k*EP+uV1], vv = Vm[k*EP+vV1];
            Vm[k*EP+uV1] = c2*vu - s2*vv;
            Vm[k*EP+vV1] = fmaf(s2, vu, c2*vv);
          }
        }
        uA  = (uA  == 0) ? 0 : ((uA  == 63) ? 1 : uA  + 1);
        vA  = (vA  == 63) ? 1 : vA  + 1;
        uV0 = (uV0 == 0) ? 0 : ((uV0 == 63) ? 1 : uV0 + 1);
        vV0 = (vV0 == 63) ? 1 : vV0 + 1;
        uV1 = (uV1 == 63) ? 1 : uV1 + 1;
        vV1 = (vV1 == 63) ? 1 : vV1 + 1;
        __syncthreads();
      }
    }
    for (int i = tid; i < 4096; i += 1024) ws[WS_V + i] = Vm[(i >> 6)*EP + (i & 63)];
    if (tid < 64) ws[WS_LAM + tid] = Am[tid*(EP+1)];
  } else if (blk <= nRng) {
    // ---- RNG producer: exact k_main DRAW+SPLIT, packed f16hi|f16lo u32.
    // L = consumer's linear thread id (blockIdx*256 + tid in k_main).
    const int L = (blk - 1) * 1024 + tid;
    const int bI = L >> 8, t256 = L & 255;
    const int wv = t256 >> 6, lane = t256 & 63;
    const int cw = lane & 15, g4 = lane >> 4;
    const int koff = g4 * 8;
    const int trajBase = bI * 64 + wv * 16;
    const uint32_t base = (uint32_t)(trajBase + cw) * 64u;
    uint32_t* wsu = (uint32_t*)ws;
    uint32_t* rngL = wsu + WS_RNG + (size_t)L * 16u * (unsigned)nS;
    for (int j = 1; j <= nS; ++j) {
      const uint32_t k0 = P.fk0[j-1], k1 = P.fk1[j-1];
      uint32_t ov[16];
#pragma unroll
      for (int i = 0; i < 8; ++i) { float dd; DRAW(dd, koff + i) PACKD(ov[i], dd) }
#pragma unroll
      for (int i = 0; i < 8; ++i) { float dd; DRAW(dd, 32 + koff + i) PACKD(ov[8+i], dd) }
      uint4_t* wr = (uint4_t*)(rngL + (size_t)(j-1)*16);
      wr[0] = (uint4_t){ov[0], ov[1], ov[2], ov[3]};
      wr[1] = (uint4_t){ov[4], ov[5], ov[6], ov[7]};
      wr[2] = (uint4_t){ov[8], ov[9], ov[10], ov[11]};
      wr[3] = (uint4_t){ov[12], ov[13], ov[14], ov[15]};
    }
  } else {
    // ---- setup2: amu[b][d] = (mu A)[d] ; f[b][d] = c - mu - amu
    int t = (blk - 1 - nRng) * 1024 + tid;
    if (t < 8192) {
      int b = t >> 6, d = t & 63;
      float s = 0;
      for (int m = 0; m < 64; ++m) s = fmaf(ws[WS_MU + b*64+m], ws[WS_A + m*64+d], s);
      ws[WS_AMU + t] = s;
      ws[WS_F + t] = ws[WS_C + t] - ws[WS_MU + t] - s;
    }
  }
}

// ---- setupfv (fz + VF + wconst): blocks 0-31: fz = f V; blocks 32-35: pack V
// into f16 hi/lo MFMA B-fragments; block 36: wconst[b].
__global__ void k_setupfv(float* __restrict__ ws) {
  int blk = blockIdx.x;
  if (blk < 32) {
    int t = blk * 256 + threadIdx.x;
    int b = t >> 6, d = t & 63;
    float s = 0;
    for (int m = 0; m < 64; ++m) s = fmaf(ws[WS_F + b*64+m], ws[WS_V + m*64+d], s);
    ws[WS_FZ + t] = s;
  } else if (blk < 36) {
    int idx = (blk - 32) * 256 + threadIdx.x;   // 0..1023
    int lane = idx & 63, F = idx >> 6;
    int t = F >> 3, kt = (F >> 2) & 1, nt = F & 3;
    int n = nt*16 + (lane & 15);
    int k0 = kt*32 + ((lane >> 4) & 3)*8;
    uint32_t out[4];
    for (int jj = 0; jj < 4; ++jj) {
      float v0 = ws[WS_V + (k0 + 2*jj    )*64 + n];
      float v1 = ws[WS_V + (k0 + 2*jj + 1)*64 + n];
      _Float16 h0, h1;
      if (t == 0) { h0 = (_Float16)v0; h1 = (_Float16)v1; }
      else {
        _Float16 a0 = (_Float16)v0, a1 = (_Float16)v1;
        h0 = (_Float16)(v0 - (float)a0);
        h1 = (_Float16)(v1 - (float)a1);
      }
      unsigned short u0 = __builtin_bit_cast(unsigned short, h0);
      unsigned short u1 = __builtin_bit_cast(unsigned short, h1);
      out[jj] = (uint32_t)u0 | ((uint32_t)u1 << 16);
    }
    uint32_t* dst = (uint32_t*)ws + WS_VF + idx*4;
    dst[0] = out[0]; dst[1] = out[1]; dst[2] = out[2]; dst[3] = out[3];
  } else {
    int b = threadIdx.x;
    if (b < 128) {
      float muc = 0, musq = 0, muamu = 0;
      for (int d = 0; d < 64; ++d) {
        float m = ws[WS_MU + b*64+d];
        muc   = fmaf(m, ws[WS_C + b*64+d], muc);
        musq  = fmaf(m, m, musq);
        muamu = fmaf(m, ws[WS_AMU + b*64+d], muamu);
      }
      ws[WS_WC + b] = -32.0f * LOG2PI - 0.5f * ws[WS_XSQ + b]
                      + muc - 0.5f * musq - 0.5f * muamu;
    }
  }
}

// ---- k_main hot-loop macros ------------------------------------------------

#define SPLIT1(AH, AL, J, VV)                                                \
  { _Float16 hh = (_Float16)(VV); AH[J] = hh;                                \
    AL[J] = (_Float16)((VV) - (float)hh); }

#define DRAWSPLIT8(AH, AL, KB)                                               \
  { float dd;                                                                \
    DRAW(dd, (KB)+0) SPLIT1(AH, AL, 0, dd)                                   \
    DRAW(dd, (KB)+1) SPLIT1(AH, AL, 1, dd)                                   \
    DRAW(dd, (KB)+2) SPLIT1(AH, AL, 2, dd)                                   \
    DRAW(dd, (KB)+3) SPLIT1(AH, AL, 3, dd)                                   \
    DRAW(dd, (KB)+4) SPLIT1(AH, AL, 4, dd)                                   \
    DRAW(dd, (KB)+5) SPLIT1(AH, AL, 5, dd)                                   \
    DRAW(dd, (KB)+6) SPLIT1(AH, AL, 6, dd)                                   \
    DRAW(dd, (KB)+7) SPLIT1(AH, AL, 7, dd) }

#define FRAGB(T, KT, NT)                                                     \
  __builtin_bit_cast(half8_t, VF[(((T)*2+(KT))*4+(NT))*64 + lane])

#define ROT1(ZO, NT, AH0, AL0, AH1, AL1)                                     \
  { half8_t bh0 = FRAGB(0,0,NT), bh1 = FRAGB(0,1,NT);                        \
    half8_t bl0 = FRAGB(1,0,NT), bl1 = FRAGB(1,1,NT);                        \
    f4_t aa = {0.f, 0.f, 0.f, 0.f};                                          \
    aa = __builtin_amdgcn_mfma_f32_16x16x32_f16(AH0, bh0, aa, 0, 0, 0);      \
    aa = __builtin_amdgcn_mfma_f32_16x16x32_f16(AH1, bh1, aa, 0, 0, 0);      \
    aa = __builtin_amdgcn_mfma_f32_16x16x32_f16(AL0, bh0, aa, 0, 0, 0);      \
    aa = __builtin_amdgcn_mfma_f32_16x16x32_f16(AL1, bh1, aa, 0, 0, 0);      \
    aa = __builtin_amdgcn_mfma_f32_16x16x32_f16(AH0, bl0, aa, 0, 0, 0);      \
    aa = __builtin_amdgcn_mfma_f32_16x16x32_f16(AH1, bl1, aa, 0, 0, 0);      \
    ZO = aa; }

#define ROTATE4(O0, O1, O2, O3, AH0, AL0, AH1, AL1)                          \
  ROT1(O0, 0, AH0, AL0, AH1, AL1) ROT1(O1, 1, AH0, AL0, AH1, AL1)            \
  ROT1(O2, 2, AH0, AL0, AH1, AL1) ROT1(O3, 3, AH0, AL0, AH1, AL1)

// vectorized leapfrog: v_pk_fma_f32 path, IEEE-identical per component
#define LF4V(ZV, PV, NLM, FV, DBL)                                           \
  { f4_t gg = __builtin_elementwise_fma(bk4,                                 \
        __builtin_elementwise_fma(NLM, ZV, FV), -ZV);                        \
    PV = __builtin_elementwise_fma(c025v, gg, PV);                           \
    if (DBL) PV = __builtin_elementwise_fma(c025v, gg, PV);                  \
    ZV = __builtin_elementwise_fma(c005v, PV, ZV); }
#define SUBSTEPV(DBL)                                                        \
  LF4V(z0, pz0, nlm0, fzv0, DBL) LF4V(z1, pz1, nlm1, fzv1, DBL)              \
  LF4V(z2, pz2, nlm2, fzv2, DBL) LF4V(z3, pz3, nlm3, fzv3, DBL)

#define W_EVALN(WOUT)                                                        \
  { f4_t s1 = fzv0*z0 + fzv1*z1 + fzv2*z2 + fzv3*z3;                         \
    f4_t s2 = (lmS0*z0)*z0 + (lmS1*z1)*z1 + (lmS2*z2)*z2 + (lmS3*z3)*z3;     \
    f4_t vv = s1 - 0.5f*s2;                                                  \
    float r0 = vv.x, r1 = vv.y, r2 = vv.z, r3 = vv.w;                        \
    r0 += __shfl_xor(r0, 1); r1 += __shfl_xor(r1, 1);                        \
    r2 += __shfl_xor(r2, 1); r3 += __shfl_xor(r3, 1);                        \
    r0 += __shfl_xor(r0, 2); r1 += __shfl_xor(r1, 2);                        \
    r2 += __shfl_xor(r2, 2); r3 += __shfl_xor(r3, 2);                        \
    r0 += __shfl_xor(r0, 4); r1 += __shfl_xor(r1, 4);                        \
    r2 += __shfl_xor(r2, 4); r3 += __shfl_xor(r3, 4);                        \
    r0 += __shfl_xor(r0, 8); r1 += __shfl_xor(r1, 8);                        \
    r2 += __shfl_xor(r2, 8); r3 += __shfl_xor(r3, 8);                        \
    float wsel = (cw == 0) ? r0 : ((cw == 1) ? r1 : ((cw == 2) ? r2 : r3));  \
    WOUT = wsel + wcs; }

#define PLO 0x05040100u
#define PHI 0x07060302u

// ---- main: MFMA rotation; wave = 16 trajs; 4 waves/block, 2048 blocks.
// launch_bounds (256,4): 4 blocks/CU resident (VGPR<=128, LDS 64KB) -- r20.
__global__ __launch_bounds__(256, 4) void k_main(const float* __restrict__ qn,
                                                 const float* __restrict__ ws,
                                                 float* __restrict__ slw_out,
                                                 KParams P, int nS) {
  __shared__ uint4_t VF[1024];   // 16 KB: V f16 hi/lo B-fragments
  const int tid = threadIdx.x;
  {
    const uint4_t* src = (const uint4_t*)((const uint32_t*)ws + WS_VF);
    for (int i = tid; i < 1024; i += 256) VF[i] = src[i];
  }
  __syncthreads();

  const int lane = tid & 63;
  const int wv = tid >> 6;
  const int cw = lane & 15;              // MFMA col; also A-operand row m
  const int g4 = lane >> 4;              // quad id
  const int koff = g4 * 8;               // A-fragment k offset
  const int trajBase = blockIdx.x * 64 + wv * 16;
  const uint32_t base = (uint32_t)(trajBase + cw) * 64u;   // RNG row base
  const uint32_t* rngL = (const uint32_t*)ws + WS_RNG
                       + (size_t)(blockIdx.x * 256 + tid) * 16u * (unsigned)nS;

  const int b0 = (trajBase + g4*4 + 0) & 127;
  const int b1 = (trajBase + g4*4 + 1) & 127;
  const int b2 = (trajBase + g4*4 + 2) & 127;
  const int b3 = (trajBase + g4*4 + 3) & 127;
  f4_t fzv0, fzv1, fzv2, fzv3;
  fzv0.x = ws[WS_FZ + b0*64 + cw];      fzv0.y = ws[WS_FZ + b1*64 + cw];
  fzv0.z = ws[WS_FZ + b2*64 + cw];      fzv0.w = ws[WS_FZ + b3*64 + cw];
  fzv1.x = ws[WS_FZ + b0*64 + 16 + cw]; fzv1.y = ws[WS_FZ + b1*64 + 16 + cw];
  fzv1.z = ws[WS_FZ + b2*64 + 16 + cw]; fzv1.w = ws[WS_FZ + b3*64 + 16 + cw];
  fzv2.x = ws[WS_FZ + b0*64 + 32 + cw]; fzv2.y = ws[WS_FZ + b1*64 + 32 + cw];
  fzv2.z = ws[WS_FZ + b2*64 + 32 + cw]; fzv2.w = ws[WS_FZ + b3*64 + 32 + cw];
  fzv3.x = ws[WS_FZ + b0*64 + 48 + cw]; fzv3.y = ws[WS_FZ + b1*64 + 48 + cw];
  fzv3.z = ws[WS_FZ + b2*64 + 48 + cw]; fzv3.w = ws[WS_FZ + b3*64 + 48 + cw];
  const float lmS0 = ws[WS_LAM + cw];
  const float lmS1 = ws[WS_LAM + 16 + cw];
  const float lmS2 = ws[WS_LAM + 32 + cw];
  const float lmS3 = ws[WS_LAM + 48 + cw];
  const float wcs = ws[WS_WC + ((trajBase + g4*4 + (cw & 3)) & 127)];
  const f4_t nlm0 = {-lmS0, -lmS0, -lmS0, -lmS0};
  const f4_t nlm1 = {-lmS1, -lmS1, -lmS1, -lmS1};
  const f4_t nlm2 = {-lmS2, -lmS2, -lmS2, -lmS2};
  const f4_t nlm3 = {-lmS3, -lmS3, -lmS3, -lmS3};
  const f4_t c025v = {0.025f, 0.025f, 0.025f, 0.025f};
  const f4_t c005v = {0.05f, 0.05f, 0.05f, 0.05f};

  f4_t z0, z1, z2, z3, pz0, pz1, pz2, pz3;
  float slw = 0.0f;

  // j = 0: z0 = qn . V  (qn read at A-fragment positions; f16 3-term split)
  {
    const float* qp = qn + (size_t)base;
    f4_t qa = *(const f4_t*)(qp + koff);
    f4_t qb = *(const f4_t*)(qp + koff + 4);
    f4_t qc = *(const f4_t*)(qp + 32 + koff);
    f4_t qd = *(const f4_t*)(qp + 32 + koff + 4);
    half8_t ah0, al0, ah1, al1;
    SPLIT1(ah0, al0, 0, qa.x) SPLIT1(ah0, al0, 1, qa.y)
    SPLIT1(ah0, al0, 2, qa.z) SPLIT1(ah0, al0, 3, qa.w)
    SPLIT1(ah0, al0, 4, qb.x) SPLIT1(ah0, al0, 5, qb.y)
    SPLIT1(ah0, al0, 6, qb.z) SPLIT1(ah0, al0, 7, qb.w)
    SPLIT1(ah1, al1, 0, qc.x) SPLIT1(ah1, al1, 1, qc.y)
    SPLIT1(ah1, al1, 2, qc.z) SPLIT1(ah1, al1, 3, qc.w)
    SPLIT1(ah1, al1, 4, qd.x) SPLIT1(ah1, al1, 5, qd.y)
    SPLIT1(ah1, al1, 6, qd.z) SPLIT1(ah1, al1, 7, qd.w)
    ROTATE4(z0, z1, z2, z3, ah0, al0, ah1, al1)
  }
  {
    float w0;
    W_EVALN(w0);
    slw = fmaf(P.dbeta[0], w0, slw);
  }

  for (int j = 1; j <= 16; ++j) {
    const float bk = P.beta[j];
    const f4_t bk4 = {bk, bk, bk, bk};
    half8_t ah0, al0, ah1, al1;
    if (j <= nS) {
      // staged: load packed f16hi|f16lo draws, unpack via v_perm
      const uint4_t* rr = (const uint4_t*)(rngL + (size_t)(j-1)*16);
      uint4_t q0 = rr[0], q1 = rr[1], q2 = rr[2], q3 = rr[3];
      uint4_t uh0 = { __builtin_amdgcn_perm(q0.y, q0.x, PLO),
                      __builtin_amdgcn_perm(q0.w, q0.z, PLO),
                      __builtin_amdgcn_perm(q1.y, q1.x, PLO),
                      __builtin_amdgcn_perm(q1.w, q1.z, PLO) };
      uint4_t ul0 = { __builtin_amdgcn_perm(q0.y, q0.x, PHI),
                      __builtin_amdgcn_perm(q0.w, q0.z, PHI),
                      __builtin_amdgcn_perm(q1.y, q1.x, PHI),
                      __builtin_amdgcn_perm(q1.w, q1.z, PHI) };
      uint4_t uh1 = { __builtin_amdgcn_perm(q2.y, q2.x, PLO),
                      __builtin_amdgcn_perm(q2.w, q2.z, PLO),
                      __builtin_amdgcn_perm(q3.y, q3.x, PLO),
                      __builtin_amdgcn_perm(q3.w, q3.z, PLO) };
      uint4_t ul1 = { __builtin_amdgcn_perm(q2.y, q2.x, PHI),
                      __builtin_amdgcn_perm(q2.w, q2.z, PHI),
                      __builtin_amdgcn_perm(q3.y, q3.x, PHI),
                      __builtin_amdgcn_perm(q3.w, q3.z, PHI) };
      ah0 = __builtin_bit_cast(half8_t, uh0);
      al0 = __builtin_bit_cast(half8_t, ul0);
      ah1 = __builtin_bit_cast(half8_t, uh1);
      al1 = __builtin_bit_cast(half8_t, ul1);
    } else {
      const uint32_t k0 = P.fk0[j-1], k1 = P.fk1[j-1];
      DRAWSPLIT8(ah0, al0, koff)
      DRAWSPLIT8(ah1, al1, 32 + koff)
    }
    ROTATE4(pz0, pz1, pz2, pz3, ah0, al0, ah1, al1)   // pz = p . V
    SUBSTEPV(false)
    SUBSTEPV(true)
    SUBSTEPV(true)
    float wj;
    W_EVALN(wj);
    slw = fmaf(P.dbeta[j], wj, slw);
  }
  if (cw < 4) slw_out[trajBase + g4*4 + cw] = slw;
}

// ---- logsumexp over n per batch column b
__global__ void k_reduce(const float* __restrict__ slw, float* __restrict__ out) {
  __shared__ float red[256];
  int b = blockIdx.x, t = threadIdx.x;
  float v0 = slw[t*128 + b];
  float v1 = slw[(t+256)*128 + b];
  float v2 = slw[(t+512)*128 + b];
  float v3 = slw[(t+768)*128 + b];
  float m = fmaxf(fmaxf(v0, v1), fmaxf(v2, v3));
  red[t] = m; __syncthreads();
  for (int s = 128; s > 0; s >>= 1) {
    if (t < s) red[t] = fmaxf(red[t], red[t+s]);
    __syncthreads();
  }
  m = red[0]; __syncthreads();
  float sum = expf(v0 - m) + expf(v1 - m) + expf(v2 - m) + expf(v3 - m);
  red[t] = sum; __syncthreads();
  for (int s = 128; s > 0; s >>= 1) {
    if (t < s) red[t] += red[t+s];
    __syncthreads();
  }
  if (t == 0) out[b] = m + logf(red[0]) - 6.93147180559945309f;  // - log(1024)
}

extern "C" void kernel_launch(void* const* d_in, const int* in_sizes, int n_in,
                              void* d_out, int out_size, void* d_ws, size_t ws_size,
                              hipStream_t stream) {
  const float* x    = (const float*)d_in[0];
  const float* Wenc = (const float*)d_in[1];
  const float* Wdec = (const float*)d_in[2];
  const float* qn   = (const float*)d_in[3];
  // d_in[4] (p_noise) is dead: momentum fully resampled every anneal step.
  float* ws  = (float*)d_ws;
  float* out = (float*)d_out;
  if (ws_size < (size_t)WS_TOTAL * sizeof(float)) return;

  // staged-RNG step count from available workspace (33.55 MB per step)
  size_t avail_u32 = ws_size / 4;
  int nS = 0;
  if (avail_u32 > (size_t)WS_RNG) {
    nS = (int)((avail_u32 - (size_t)WS_RNG) / 8388608ull);  // 524288*16 u32/step
    if (nS > 16) nS = 16;
  }
  const int nRng = (nS > 0) ? 512 : 0;

  KParams P;
  double bb[18];
  for (int i = 0; i < 18; ++i) {
    double tt = (double)i / 17.0;
    bb[i] = 1.0 / (1.0 + exp(-(8.0 * tt - 4.0)));
  }
  for (int i = 0; i < 18; ++i) P.beta[i] = (float)((bb[i] - bb[0]) / (bb[17] - bb[0]));
  for (int j = 0; j <= 16; ++j) P.dbeta[j] = P.beta[j+1] - P.beta[j];
  for (int k = 1; k <= 16; ++k) {
    uint32_t a, c;
    threefry2x32(0u, 42u, 0u, (uint32_t)k, a, c);  // fold_in(key(42), k)
    P.fk0[k-1] = a; P.fk1[k-1] = c;
  }

  hipLaunchKernelGGL(k_setup1, dim3(81), dim3(256), 0, stream, x, Wenc, Wdec, ws);
  hipLaunchKernelGGL(k_fused, dim3(1 + nRng + 8), dim3(1024), 0, stream, ws, P, nRng, nS);
  hipLaunchKernelGGL(k_setupfv, dim3(37), dim3(256), 0, stream, ws);
  hipLaunchKernelGGL(k_main, dim3(2048), dim3(256), 0, stream, qn, ws, ws + WS_SLW, P, nS);
  hipLaunchKernelGGL(k_reduce, dim3(128), dim3(256), 0, stream, ws + WS_SLW, out);
}

// Round 6
// 621.861 us; speedup vs baseline: 1.2319x; 1.2319x over previous
//
#include <hip/hip_runtime.h>
#include <math.h>
#include <stdint.h>

// AIS estimator: N=1024 samples, B=128, DIM=DX=64, K=16 anneal steps, 3 leapfrog.
// Round 21: undo r20's spill. (256,4) made the compiler clamp VGPR 100->64 and
// spill all state (FETCH 136->950MB, WRITE 0.5->109MB, k_main 321->456us).
// Fix: __launch_bounds__(256) only (no min-waves arg). At VGPR~100-104 the HW
// occupancy is naturally 4 waves/SIMD (~50%), double r19's self-imposed cap
// (arg=2 -> 25% ceiling, observed 21%), with zero spill risk.
// Everything else identical to r19 (616us):
//  - k_fused: block 0 = k_eig (r18); blocks 1..512 = RNG producer (exact
//    DRAW+SPLIT, packed f16hi|f16lo u32); blocks 513..520 = setup2.
//    RNG for the first nS steps hides under eig's ~250us (free).
//  - k_main: j<=nS loads staged draws (dwordx4 + v_perm); nS from ws_size
//    (observed nS=4: FETCH 136MB = 4 x 33.5MB).
//  - leapfrog via v_pk_fma_f32 (__builtin_elementwise_fma), IEEE-identical.
// All staged bits flow through identical expressions -> absmax 1.0 preserved.

#define WS_A     0
#define WS_MU    4096
#define WS_C     12288
#define WS_XSQ   20480
#define WS_AMU   20608
#define WS_F     28800
#define WS_WC    36992
#define WS_V     37120
#define WS_LAM   41216
#define WS_FZ    41280
#define WS_VF    49472
#define WS_SLW   53568
#define WS_TOTAL (WS_SLW + 131072)
#define WS_RNG   (WS_SLW + 131072)   // optional u32 region: 524288*16*nS

#define LOG2PI 1.8378770664093453f

typedef _Float16 half8_t __attribute__((ext_vector_type(8)));
typedef float f4_t __attribute__((ext_vector_type(4)));
typedef unsigned int uint4_t __attribute__((ext_vector_type(4)));

struct KParams {
  float beta[18];
  float dbeta[17];
  uint32_t fk0[16];
  uint32_t fk1[16];
};

__host__ __device__ static inline void threefry2x32(uint32_t ks0, uint32_t ks1,
                                                    uint32_t x0, uint32_t x1,
                                                    uint32_t& o0, uint32_t& o1) {
  uint32_t ks2 = ks0 ^ ks1 ^ 0x1BD11BDAu;
  x0 += ks0; x1 += ks1;
#define TFR(r) { x0 += x1; x1 = (x1 << (r)) | (x1 >> (32 - (r))); x1 ^= x0; }
  TFR(13) TFR(15) TFR(26) TFR(6)
  x0 += ks1; x1 += ks2 + 1u;
  TFR(17) TFR(29) TFR(16) TFR(24)
  x0 += ks2; x1 += ks0 + 2u;
  TFR(13) TFR(15) TFR(26) TFR(6)
  x0 += ks0; x1 += ks1 + 3u;
  TFR(17) TFR(29) TFR(16) TFR(24)
  x0 += ks1; x1 += ks2 + 4u;
  TFR(13) TFR(15) TFR(26) TFR(6)
  x0 += ks2; x1 += ks0 + 5u;
#undef TFR
  o0 = x0; o1 = x1;
}

__device__ __forceinline__ float u_from_bits(uint32_t bits) {
  const float LO = __uint_as_float(0xBF7FFFFFu);  // nextafter(-1,0) in f32
  float f = __uint_as_float((bits >> 9) | 0x3F800000u) - 1.0f;
  return fmaf(f, 2.0f, LO);
}

// XLA ErfInv32 (Giles); __logf variant validated r11-r14 (absmax = 1 bf16 ulp)
__device__ __forceinline__ float erfinv_f(float x) {
  float w = -__logf(fmaf(-x, x, 1.0f));
  float p;
  if (w < 5.0f) {
    w -= 2.5f;
    p = 2.81022636e-08f;
    p = fmaf(p, w, 3.43273939e-07f);
    p = fmaf(p, w, -3.5233877e-06f);
    p = fmaf(p, w, -4.39150654e-06f);
    p = fmaf(p, w, 0.00021858087f);
    p = fmaf(p, w, -0.00125372503f);
    p = fmaf(p, w, -0.00417768164f);
    p = fmaf(p, w, 0.246640727f);
    p = fmaf(p, w, 1.50140941f);
  } else {
    w = sqrtf(w) - 3.0f;
    p = -0.000200214257f;
    p = fmaf(p, w, 0.000100950558f);
    p = fmaf(p, w, 0.00134934322f);
    p = fmaf(p, w, -0.00367342844f);
    p = fmaf(p, w, 0.00573950773f);
    p = fmaf(p, w, -0.0076224613f);
    p = fmaf(p, w, 0.00943887047f);
    p = fmaf(p, w, 1.00167406f);
    p = fmaf(p, w, 2.83297682f);
  }
  return p * x;
}

// ---- setup1: A = Wdec Wdec^T ; mu[b][d] ; c[b][d] ; xsq[b]
__global__ void k_setup1(const float* __restrict__ x, const float* __restrict__ Wenc,
                         const float* __restrict__ Wdec, float* __restrict__ ws) {
  int t = blockIdx.x * 256 + threadIdx.x;
  if (t < 4096) {
    int i = t >> 6, j = t & 63;
    float s = 0;
    for (int e = 0; e < 64; ++e) s = fmaf(Wdec[i*64+e], Wdec[j*64+e], s);
    ws[WS_A + t] = s;
  } else if (t < 12288) {
    int u = t - 4096; int b = u >> 6, d = u & 63;
    float s = 0;
    for (int e = 0; e < 64; ++e) s = fmaf(x[b*64+e], Wenc[e*64+d], s);
    ws[WS_MU + u] = s;
  } else if (t < 20480) {
    int u = t - 12288; int b = u >> 6, d = u & 63;
    float s = 0;
    for (int e = 0; e < 64; ++e) s = fmaf(x[b*64+e], Wdec[d*64+e], s);
    ws[WS_C + u] = s;
  } else if (t < 20608) {
    int b = t - 20480;
    float s = 0;
    for (int e = 0; e < 64; ++e) s = fmaf(x[b*64+e], x[b*64+e], s);
    ws[WS_XSQ + b] = s;
  }
}

#define DRAW(PC, IDX)                                                        \
  { uint32_t o0, o1;                                                         \
    threefry2x32(k0, k1, 0u, base + (IDX), o0, o1);                          \
    PC = 1.41421356f * erfinv_f(u_from_bits(o0 ^ o1)); }

#define PACKD(DST, DD)                                                       \
  { _Float16 hh = (_Float16)(DD);                                            \
    _Float16 ll = (_Float16)((DD) - (float)hh);                              \
    DST = (uint32_t)__builtin_bit_cast(unsigned short, hh) |                 \
          ((uint32_t)__builtin_bit_cast(unsigned short, ll) << 16); }

// ---- k_fused: block 0 = k_eig (r18 version); blocks 1..nRng = RNG producer;
// blocks nRng+1..nRng+8 = setup2. All roles independent (no inter-block deps).
#define EP 65
__global__ __launch_bounds__(1024) void k_fused(float* __restrict__ ws, KParams P,
                                                int nRng, int nS) {
  const int blk = blockIdx.x;
  const int tid = threadIdx.x;
  if (blk == 0) {
    // ---- cyclic Jacobi, 4 sweeps x 63 rounds, pitch 65 (r18, bit-identical)
    __shared__ float Am[64 * EP];
    __shared__ float Vm[64 * EP];
    __shared__ float cs_c[32], cs_s[32];
    __shared__ int ppu[32], ppv[32];
    for (int i = tid; i < 4096; i += 1024) {
      int r = i >> 6, c = i & 63;
      Am[r*EP + c] = ws[WS_A + i];
      Vm[r*EP + c] = (r == c) ? 1.0f : 0.0f;
    }
    const int pA = tid & 31;
    int uA = (pA == 0) ? 0 : pA;
    int vA = (pA == 0) ? 63 : (63 - pA);
    const int pV0 = tid >> 6;
    int uV0 = (pV0 == 0) ? 0 : pV0;
    int vV0 = (pV0 == 0) ? 63 : (63 - pV0);
    const int pV1 = 16 + pV0;
    int uV1 = pV1;
    int vV1 = 63 - pV1;
    __syncthreads();
    for (int sweep = 0; sweep < 4; ++sweep) {
      for (int r = 0; r < 63; ++r) {
        if (tid < 32) {
          float app = Am[uA*(EP+1)], aqq = Am[vA*(EP+1)], apq = Am[uA*EP+vA];
          float c = 1.0f, s = 0.0f;
          if (fabsf(apq) > 1e-30f) {
            float tau = (aqq - app) / (2.0f * apq);
            float t = copysignf(1.0f / (fabsf(tau) + sqrtf(fmaf(tau, tau, 1.0f))), tau);
            c = 1.0f / sqrtf(fmaf(t, t, 1.0f));
            s = t * c;
          }
          ppu[tid] = uA; ppv[tid] = vA; cs_c[tid] = c; cs_s[tid] = s;
        }
        __syncthreads();
        {
          int i = tid >> 5;
          int ui = ppu[i], vi = ppv[i];
          const int uj = uA, vj = vA;
          float ci = cs_c[i], si = cs_s[i], cj = cs_c[pA], sj = cs_s[pA];
          float a = Am[ui*EP+uj], bb = Am[ui*EP+vj];
          float d = Am[vi*EP+uj], e  = Am[vi*EP+vj];
          float r0u = ci*a  - si*d;
          float r1u = fmaf(si, a,  ci*d);
          float r0v = ci*bb - si*e;
          float r1v = fmaf(si, bb, ci*e);
          Am[ui*EP+uj] = cj*r0u - sj*r0v;
          Am[ui*EP+vj] = fmaf(sj, r0u, cj*r0v);
          Am[vi*EP+uj] = cj*r1u - sj*r1v;
          Am[vi*EP+vj] = fmaf(sj, r1u, cj*r1v);
        }
        {
          const int k = tid & 63;
          {
            float c2 = cs_c[pV0], s2 = cs_s[pV0];
            float vu = Vm[k*EP+uV0], vv = Vm[k*EP+vV0];
            Vm[k*EP+uV0] = c2*vu - s2*vv;
            Vm[k*EP+vV0] = fmaf(s2, vu, c2*vv);
          }
          {
            float c2 = cs_c[pV1], s2 = cs_s[pV1];
            float vu = Vm[k*EP+uV1], vv = Vm[k*EP+vV1];
            Vm[k*EP+uV1] = c2*vu - s2*vv;
            Vm[k*EP+vV1] = fmaf(s2, vu, c2*vv);
          }
        }
        uA  = (uA  == 0) ? 0 : ((uA  == 63) ? 1 : uA  + 1);
        vA  = (vA  == 63) ? 1 : vA  + 1;
        uV0 = (uV0 == 0) ? 0 : ((uV0 == 63) ? 1 : uV0 + 1);
        vV0 = (vV0 == 63) ? 1 : vV0 + 1;
        uV1 = (uV1 == 63) ? 1 : uV1 + 1;
        vV1 = (vV1 == 63) ? 1 : vV1 + 1;
        __syncthreads();
      }
    }
    for (int i = tid; i < 4096; i += 1024) ws[WS_V + i] = Vm[(i >> 6)*EP + (i & 63)];
    if (tid < 64) ws[WS_LAM + tid] = Am[tid*(EP+1)];
  } else if (blk <= nRng) {
    // ---- RNG producer: exact k_main DRAW+SPLIT, packed f16hi|f16lo u32.
    // L = consumer's linear thread id (blockIdx*256 + tid in k_main).
    const int L = (blk - 1) * 1024 + tid;
    const int bI = L >> 8, t256 = L & 255;
    const int wv = t256 >> 6, lane = t256 & 63;
    const int cw = lane & 15, g4 = lane >> 4;
    const int koff = g4 * 8;
    const int trajBase = bI * 64 + wv * 16;
    const uint32_t base = (uint32_t)(trajBase + cw) * 64u;
    uint32_t* wsu = (uint32_t*)ws;
    uint32_t* rngL = wsu + WS_RNG + (size_t)L * 16u * (unsigned)nS;
    for (int j = 1; j <= nS; ++j) {
      const uint32_t k0 = P.fk0[j-1], k1 = P.fk1[j-1];
      uint32_t ov[16];
#pragma unroll
      for (int i = 0; i < 8; ++i) { float dd; DRAW(dd, koff + i) PACKD(ov[i], dd) }
#pragma unroll
      for (int i = 0; i < 8; ++i) { float dd; DRAW(dd, 32 + koff + i) PACKD(ov[8+i], dd) }
      uint4_t* wr = (uint4_t*)(rngL + (size_t)(j-1)*16);
      wr[0] = (uint4_t){ov[0], ov[1], ov[2], ov[3]};
      wr[1] = (uint4_t){ov[4], ov[5], ov[6], ov[7]};
      wr[2] = (uint4_t){ov[8], ov[9], ov[10], ov[11]};
      wr[3] = (uint4_t){ov[12], ov[13], ov[14], ov[15]};
    }
  } else {
    // ---- setup2: amu[b][d] = (mu A)[d] ; f[b][d] = c - mu - amu
    int t = (blk - 1 - nRng) * 1024 + tid;
    if (t < 8192) {
      int b = t >> 6, d = t & 63;
      float s = 0;
      for (int m = 0; m < 64; ++m) s = fmaf(ws[WS_MU + b*64+m], ws[WS_A + m*64+d], s);
      ws[WS_AMU + t] = s;
      ws[WS_F + t] = ws[WS_C + t] - ws[WS_MU + t] - s;
    }
  }
}

// ---- setupfv (fz + VF + wconst): blocks 0-31: fz = f V; blocks 32-35: pack V
// into f16 hi/lo MFMA B-fragments; block 36: wconst[b].
__global__ void k_setupfv(float* __restrict__ ws) {
  int blk = blockIdx.x;
  if (blk < 32) {
    int t = blk * 256 + threadIdx.x;
    int b = t >> 6, d = t & 63;
    float s = 0;
    for (int m = 0; m < 64; ++m) s = fmaf(ws[WS_F + b*64+m], ws[WS_V + m*64+d], s);
    ws[WS_FZ + t] = s;
  } else if (blk < 36) {
    int idx = (blk - 32) * 256 + threadIdx.x;   // 0..1023
    int lane = idx & 63, F = idx >> 6;
    int t = F >> 3, kt = (F >> 2) & 1, nt = F & 3;
    int n = nt*16 + (lane & 15);
    int k0 = kt*32 + ((lane >> 4) & 3)*8;
    uint32_t out[4];
    for (int jj = 0; jj < 4; ++jj) {
      float v0 = ws[WS_V + (k0 + 2*jj    )*64 + n];
      float v1 = ws[WS_V + (k0 + 2*jj + 1)*64 + n];
      _Float16 h0, h1;
      if (t == 0) { h0 = (_Float16)v0; h1 = (_Float16)v1; }
      else {
        _Float16 a0 = (_Float16)v0, a1 = (_Float16)v1;
        h0 = (_Float16)(v0 - (float)a0);
        h1 = (_Float16)(v1 - (float)a1);
      }
      unsigned short u0 = __builtin_bit_cast(unsigned short, h0);
      unsigned short u1 = __builtin_bit_cast(unsigned short, h1);
      out[jj] = (uint32_t)u0 | ((uint32_t)u1 << 16);
    }
    uint32_t* dst = (uint32_t*)ws + WS_VF + idx*4;
    dst[0] = out[0]; dst[1] = out[1]; dst[2] = out[2]; dst[3] = out[3];
  } else {
    int b = threadIdx.x;
    if (b < 128) {
      float muc = 0, musq = 0, muamu = 0;
      for (int d = 0; d < 64; ++d) {
        float m = ws[WS_MU + b*64+d];
        muc   = fmaf(m, ws[WS_C + b*64+d], muc);
        musq  = fmaf(m, m, musq);
        muamu = fmaf(m, ws[WS_AMU + b*64+d], muamu);
      }
      ws[WS_WC + b] = -32.0f * LOG2PI - 0.5f * ws[WS_XSQ + b]
                      + muc - 0.5f * musq - 0.5f * muamu;
    }
  }
}

// ---- k_main hot-loop macros ------------------------------------------------

#define SPLIT1(AH, AL, J, VV)                                                \
  { _Float16 hh = (_Float16)(VV); AH[J] = hh;                                \
    AL[J] = (_Float16)((VV) - (float)hh); }

#define DRAWSPLIT8(AH, AL, KB)                                               \
  { float dd;                                                                \
    DRAW(dd, (KB)+0) SPLIT1(AH, AL, 0, dd)                                   \
    DRAW(dd, (KB)+1) SPLIT1(AH, AL, 1, dd)                                   \
    DRAW(dd, (KB)+2) SPLIT1(AH, AL, 2, dd)                                   \
    DRAW(dd, (KB)+3) SPLIT1(AH, AL, 3, dd)                                   \
    DRAW(dd, (KB)+4) SPLIT1(AH, AL, 4, dd)                                   \
    DRAW(dd, (KB)+5) SPLIT1(AH, AL, 5, dd)                                   \
    DRAW(dd, (KB)+6) SPLIT1(AH, AL, 6, dd)                                   \
    DRAW(dd, (KB)+7) SPLIT1(AH, AL, 7, dd) }

#define FRAGB(T, KT, NT)                                                     \
  __builtin_bit_cast(half8_t, VF[(((T)*2+(KT))*4+(NT))*64 + lane])

#define ROT1(ZO, NT, AH0, AL0, AH1, AL1)                                     \
  { half8_t bh0 = FRAGB(0,0,NT), bh1 = FRAGB(0,1,NT);                        \
    half8_t bl0 = FRAGB(1,0,NT), bl1 = FRAGB(1,1,NT);                        \
    f4_t aa = {0.f, 0.f, 0.f, 0.f};                                          \
    aa = __builtin_amdgcn_mfma_f32_16x16x32_f16(AH0, bh0, aa, 0, 0, 0);      \
    aa = __builtin_amdgcn_mfma_f32_16x16x32_f16(AH1, bh1, aa, 0, 0, 0);      \
    aa = __builtin_amdgcn_mfma_f32_16x16x32_f16(AL0, bh0, aa, 0, 0, 0);      \
    aa = __builtin_amdgcn_mfma_f32_16x16x32_f16(AL1, bh1, aa, 0, 0, 0);      \
    aa = __builtin_amdgcn_mfma_f32_16x16x32_f16(AH0, bl0, aa, 0, 0, 0);      \
    aa = __builtin_amdgcn_mfma_f32_16x16x32_f16(AH1, bl1, aa, 0, 0, 0);      \
    ZO = aa; }

#define ROTATE4(O0, O1, O2, O3, AH0, AL0, AH1, AL1)                          \
  ROT1(O0, 0, AH0, AL0, AH1, AL1) ROT1(O1, 1, AH0, AL0, AH1, AL1)            \
  ROT1(O2, 2, AH0, AL0, AH1, AL1) ROT1(O3, 3, AH0, AL0, AH1, AL1)

// vectorized leapfrog: v_pk_fma_f32 path, IEEE-identical per component
#define LF4V(ZV, PV, NLM, FV, DBL)                                           \
  { f4_t gg = __builtin_elementwise_fma(bk4,                                 \
        __builtin_elementwise_fma(NLM, ZV, FV), -ZV);                        \
    PV = __builtin_elementwise_fma(c025v, gg, PV);                           \
    if (DBL) PV = __builtin_elementwise_fma(c025v, gg, PV);                  \
    ZV = __builtin_elementwise_fma(c005v, PV, ZV); }
#define SUBSTEPV(DBL)                                                        \
  LF4V(z0, pz0, nlm0, fzv0, DBL) LF4V(z1, pz1, nlm1, fzv1, DBL)              \
  LF4V(z2, pz2, nlm2, fzv2, DBL) LF4V(z3, pz3, nlm3, fzv3, DBL)

#define W_EVALN(WOUT)                                                        \
  { f4_t s1 = fzv0*z0 + fzv1*z1 + fzv2*z2 + fzv3*z3;                         \
    f4_t s2 = (lmS0*z0)*z0 + (lmS1*z1)*z1 + (lmS2*z2)*z2 + (lmS3*z3)*z3;     \
    f4_t vv = s1 - 0.5f*s2;                                                  \
    float r0 = vv.x, r1 = vv.y, r2 = vv.z, r3 = vv.w;                        \
    r0 += __shfl_xor(r0, 1); r1 += __shfl_xor(r1, 1);                        \
    r2 += __shfl_xor(r2, 1); r3 += __shfl_xor(r3, 1);                        \
    r0 += __shfl_xor(r0, 2); r1 += __shfl_xor(r1, 2);                        \
    r2 += __shfl_xor(r2, 2); r3 += __shfl_xor(r3, 2);                        \
    r0 += __shfl_xor(r0, 4); r1 += __shfl_xor(r1, 4);                        \
    r2 += __shfl_xor(r2, 4); r3 += __shfl_xor(r3, 4);                        \
    r0 += __shfl_xor(r0, 8); r1 += __shfl_xor(r1, 8);                        \
    r2 += __shfl_xor(r2, 8); r3 += __shfl_xor(r3, 8);                        \
    float wsel = (cw == 0) ? r0 : ((cw == 1) ? r1 : ((cw == 2) ? r2 : r3));  \
    WOUT = wsel + wcs; }

#define PLO 0x05040100u
#define PHI 0x07060302u

// ---- main: MFMA rotation; wave = 16 trajs; 4 waves/block, 2048 blocks.
// __launch_bounds__(256) only: no min-waves constraint -> compiler keeps
// VGPR ~100 (no spill); HW occupancy 4 waves/SIMD (~50%) at that count. (r21)
__global__ __launch_bounds__(256) void k_main(const float* __restrict__ qn,
                                              const float* __restrict__ ws,
                                              float* __restrict__ slw_out,
                                              KParams P, int nS) {
  __shared__ uint4_t VF[1024];   // 16 KB: V f16 hi/lo B-fragments
  const int tid = threadIdx.x;
  {
    const uint4_t* src = (const uint4_t*)((const uint32_t*)ws + WS_VF);
    for (int i = tid; i < 1024; i += 256) VF[i] = src[i];
  }
  __syncthreads();

  const int lane = tid & 63;
  const int wv = tid >> 6;
  const int cw = lane & 15;              // MFMA col; also A-operand row m
  const int g4 = lane >> 4;              // quad id
  const int koff = g4 * 8;               // A-fragment k offset
  const int trajBase = blockIdx.x * 64 + wv * 16;
  const uint32_t base = (uint32_t)(trajBase + cw) * 64u;   // RNG row base
  const uint32_t* rngL = (const uint32_t*)ws + WS_RNG
                       + (size_t)(blockIdx.x * 256 + tid) * 16u * (unsigned)nS;

  const int b0 = (trajBase + g4*4 + 0) & 127;
  const int b1 = (trajBase + g4*4 + 1) & 127;
  const int b2 = (trajBase + g4*4 + 2) & 127;
  const int b3 = (trajBase + g4*4 + 3) & 127;
  f4_t fzv0, fzv1, fzv2, fzv3;
  fzv0.x = ws[WS_FZ + b0*64 + cw];      fzv0.y = ws[WS_FZ + b1*64 + cw];
  fzv0.z = ws[WS_FZ + b2*64 + cw];      fzv0.w = ws[WS_FZ + b3*64 + cw];
  fzv1.x = ws[WS_FZ + b0*64 + 16 + cw]; fzv1.y = ws[WS_FZ + b1*64 + 16 + cw];
  fzv1.z = ws[WS_FZ + b2*64 + 16 + cw]; fzv1.w = ws[WS_FZ + b3*64 + 16 + cw];
  fzv2.x = ws[WS_FZ + b0*64 + 32 + cw]; fzv2.y = ws[WS_FZ + b1*64 + 32 + cw];
  fzv2.z = ws[WS_FZ + b2*64 + 32 + cw]; fzv2.w = ws[WS_FZ + b3*64 + 32 + cw];
  fzv3.x = ws[WS_FZ + b0*64 + 48 + cw]; fzv3.y = ws[WS_FZ + b1*64 + 48 + cw];
  fzv3.z = ws[WS_FZ + b2*64 + 48 + cw]; fzv3.w = ws[WS_FZ + b3*64 + 48 + cw];
  const float lmS0 = ws[WS_LAM + cw];
  const float lmS1 = ws[WS_LAM + 16 + cw];
  const float lmS2 = ws[WS_LAM + 32 + cw];
  const float lmS3 = ws[WS_LAM + 48 + cw];
  const float wcs = ws[WS_WC + ((trajBase + g4*4 + (cw & 3)) & 127)];
  const f4_t nlm0 = {-lmS0, -lmS0, -lmS0, -lmS0};
  const f4_t nlm1 = {-lmS1, -lmS1, -lmS1, -lmS1};
  const f4_t nlm2 = {-lmS2, -lmS2, -lmS2, -lmS2};
  const f4_t nlm3 = {-lmS3, -lmS3, -lmS3, -lmS3};
  const f4_t c025v = {0.025f, 0.025f, 0.025f, 0.025f};
  const f4_t c005v = {0.05f, 0.05f, 0.05f, 0.05f};

  f4_t z0, z1, z2, z3, pz0, pz1, pz2, pz3;
  float slw = 0.0f;

  // j = 0: z0 = qn . V  (qn read at A-fragment positions; f16 3-term split)
  {
    const float* qp = qn + (size_t)base;
    f4_t qa = *(const f4_t*)(qp + koff);
    f4_t qb = *(const f4_t*)(qp + koff + 4);
    f4_t qc = *(const f4_t*)(qp + 32 + koff);
    f4_t qd = *(const f4_t*)(qp + 32 + koff + 4);
    half8_t ah0, al0, ah1, al1;
    SPLIT1(ah0, al0, 0, qa.x) SPLIT1(ah0, al0, 1, qa.y)
    SPLIT1(ah0, al0, 2, qa.z) SPLIT1(ah0, al0, 3, qa.w)
    SPLIT1(ah0, al0, 4, qb.x) SPLIT1(ah0, al0, 5, qb.y)
    SPLIT1(ah0, al0, 6, qb.z) SPLIT1(ah0, al0, 7, qb.w)
    SPLIT1(ah1, al1, 0, qc.x) SPLIT1(ah1, al1, 1, qc.y)
    SPLIT1(ah1, al1, 2, qc.z) SPLIT1(ah1, al1, 3, qc.w)
    SPLIT1(ah1, al1, 4, qd.x) SPLIT1(ah1, al1, 5, qd.y)
    SPLIT1(ah1, al1, 6, qd.z) SPLIT1(ah1, al1, 7, qd.w)
    ROTATE4(z0, z1, z2, z3, ah0, al0, ah1, al1)
  }
  {
    float w0;
    W_EVALN(w0);
    slw = fmaf(P.dbeta[0], w0, slw);
  }

  for (int j = 1; j <= 16; ++j) {
    const float bk = P.beta[j];
    const f4_t bk4 = {bk, bk, bk, bk};
    half8_t ah0, al0, ah1, al1;
    if (j <= nS) {
      // staged: load packed f16hi|f16lo draws, unpack via v_perm
      const uint4_t* rr = (const uint4_t*)(rngL + (size_t)(j-1)*16);
      uint4_t q0 = rr[0], q1 = rr[1], q2 = rr[2], q3 = rr[3];
      uint4_t uh0 = { __builtin_amdgcn_perm(q0.y, q0.x, PLO),
                      __builtin_amdgcn_perm(q0.w, q0.z, PLO),
                      __builtin_amdgcn_perm(q1.y, q1.x, PLO),
                      __builtin_amdgcn_perm(q1.w, q1.z, PLO) };
      uint4_t ul0 = { __builtin_amdgcn_perm(q0.y, q0.x, PHI),
                      __builtin_amdgcn_perm(q0.w, q0.z, PHI),
                      __builtin_amdgcn_perm(q1.y, q1.x, PHI),
                      __builtin_amdgcn_perm(q1.w, q1.z, PHI) };
      uint4_t uh1 = { __builtin_amdgcn_perm(q2.y, q2.x, PLO),
                      __builtin_amdgcn_perm(q2.w, q2.z, PLO),
                      __builtin_amdgcn_perm(q3.y, q3.x, PLO),
                      __builtin_amdgcn_perm(q3.w, q3.z, PLO) };
      uint4_t ul1 = { __builtin_amdgcn_perm(q2.y, q2.x, PHI),
                      __builtin_amdgcn_perm(q2.w, q2.z, PHI),
                      __builtin_amdgcn_perm(q3.y, q3.x, PHI),
                      __builtin_amdgcn_perm(q3.w, q3.z, PHI) };
      ah0 = __builtin_bit_cast(half8_t, uh0);
      al0 = __builtin_bit_cast(half8_t, ul0);
      ah1 = __builtin_bit_cast(half8_t, uh1);
      al1 = __builtin_bit_cast(half8_t, ul1);
    } else {
      const uint32_t k0 = P.fk0[j-1], k1 = P.fk1[j-1];
      DRAWSPLIT8(ah0, al0, koff)
      DRAWSPLIT8(ah1, al1, 32 + koff)
    }
    ROTATE4(pz0, pz1, pz2, pz3, ah0, al0, ah1, al1)   // pz = p . V
    SUBSTEPV(false)
    SUBSTEPV(true)
    SUBSTEPV(true)
    float wj;
    W_EVALN(wj);
    slw = fmaf(P.dbeta[j], wj, slw);
  }
  if (cw < 4) slw_out[trajBase + g4*4 + cw] = slw;
}

// ---- logsumexp over n per batch column b
__global__ void k_reduce(const float* __restrict__ slw, float* __restrict__ out) {
  __shared__ float red[256];
  int b = blockIdx.x, t = threadIdx.x;
  float v0 = slw[t*128 + b];
  float v1 = slw[(t+256)*128 + b];
  float v2 = slw[(t+512)*128 + b];
  float v3 = slw[(t+768)*128 + b];
  float m = fmaxf(fmaxf(v0, v1), fmaxf(v2, v3));
  red[t] = m; __syncthreads();
  for (int s = 128; s > 0; s >>= 1) {
    if (t < s) red[t] = fmaxf(red[t], red[t+s]);
    __syncthreads();
  }
  m = red[0]; __syncthreads();
  float sum = expf(v0 - m) + expf(v1 - m) + expf(v2 - m) + expf(v3 - m);
  red[t] = sum; __syncthreads();
  for (int s = 128; s > 0; s >>= 1) {
    if (t < s) red[t] += red[t+s];
    __syncthreads();
  }
  if (t == 0) out[b] = m + logf(red[0]) - 6.93147180559945309f;  // - log(1024)
}

extern "C" void kernel_launch(void* const* d_in, const int* in_sizes, int n_in,
                              void* d_out, int out_size, void* d_ws, size_t ws_size,
                              hipStream_t stream) {
  const float* x    = (const float*)d_in[0];
  const float* Wenc = (const float*)d_in[1];
  const float* Wdec = (const float*)d_in[2];
  const float* qn   = (const float*)d_in[3];
  // d_in[4] (p_noise) is dead: momentum fully resampled every anneal step.
  float* ws  = (float*)d_ws;
  float* out = (float*)d_out;
  if (ws_size < (size_t)WS_TOTAL * sizeof(float)) return;

  // staged-RNG step count from available workspace (33.55 MB per step)
  size_t avail_u32 = ws_size / 4;
  int nS = 0;
  if (avail_u32 > (size_t)WS_RNG) {
    nS = (int)((avail_u32 - (size_t)WS_RNG) / 8388608ull);  // 524288*16 u32/step
    if (nS > 16) nS = 16;
  }
  const int nRng = (nS > 0) ? 512 : 0;

  KParams P;
  double bb[18];
  for (int i = 0; i < 18; ++i) {
    double tt = (double)i / 17.0;
    bb[i] = 1.0 / (1.0 + exp(-(8.0 * tt - 4.0)));
  }
  for (int i = 0; i < 18; ++i) P.beta[i] = (float)((bb[i] - bb[0]) / (bb[17] - bb[0]));
  for (int j = 0; j <= 16; ++j) P.dbeta[j] = P.beta[j+1] - P.beta[j];
  for (int k = 1; k <= 16; ++k) {
    uint32_t a, c;
    threefry2x32(0u, 42u, 0u, (uint32_t)k, a, c);  // fold_in(key(42), k)
    P.fk0[k-1] = a; P.fk1[k-1] = c;
  }

  hipLaunchKernelGGL(k_setup1, dim3(81), dim3(256), 0, stream, x, Wenc, Wdec, ws);
  hipLaunchKernelGGL(k_fused, dim3(1 + nRng + 8), dim3(1024), 0, stream, ws, P, nRng, nS);
  hipLaunchKernelGGL(k_setupfv, dim3(37), dim3(256), 0, stream, ws);
  hipLaunchKernelGGL(k_main, dim3(2048), dim3(256), 0, stream, qn, ws, ws + WS_SLW, P, nS);
  hipLaunchKernelGGL(k_reduce, dim3(128), dim3(256), 0, stream, ws + WS_SLW, out);
}

// Round 7
// 572.795 us; speedup vs baseline: 1.3374x; 1.0857x over previous
//
#include <hip/hip_runtime.h>
#include <math.h>
#include <stdint.h>

// AIS estimator: N=1024 samples, B=128, DIM=DX=64, K=16 anneal steps, 3 leapfrog.
// Round 22: two levers on the 622us structure (k_fused[max(eig 250, rng 70)]
// -> k_main 323 + ~45 misc):
//  - k_eig sweeps 4 -> 3 (189 rounds, -62us). First non-bit-identical change:
//    off-diag ~1e-4 rel after sweep 3 (quadratic convergence); perturbation
//    analysis gives delta-out << 1 bf16 ulp (r15: absmax at 1.0-ulp floor for
//    4/5/8 sweeps alike). If absmax regresses, revert to 4.
//  - RNG cache re-laid step-major + FRACTIONAL staging of step nS+1 for the
//    first Lcut (wave-aligned) threads, sized from ws_size leftover. Bit-exact
//    (same draws, same consumption). FETCH_SIZE reveals actual ws headroom.
// r19-r21 carried: k_fused = eig + RNG producer + setup2 in one grid;
// k_main consumes staged steps (dwordx4 + v_perm), pk-fma leapfrog,
// __launch_bounds__(256) (VGPR ~108, occupancy pinned at 4 waves/SIMD --
// occupancy lever exhausted, r20 spill lesson: never force min-waves).

#define WS_A     0
#define WS_MU    4096
#define WS_C     12288
#define WS_XSQ   20480
#define WS_AMU   20608
#define WS_F     28800
#define WS_WC    36992
#define WS_V     37120
#define WS_LAM   41216
#define WS_FZ    41280
#define WS_VF    49472
#define WS_SLW   53568
#define WS_TOTAL (WS_SLW + 131072)
#define WS_RNG   (WS_SLW + 131072)   // u32 region, step-major: 8388608 u32/step
#define STEP_U32 8388608ull          // 524288 threads * 16 u32

#define LOG2PI 1.8378770664093453f

typedef _Float16 half8_t __attribute__((ext_vector_type(8)));
typedef float f4_t __attribute__((ext_vector_type(4)));
typedef unsigned int uint4_t __attribute__((ext_vector_type(4)));

struct KParams {
  float beta[18];
  float dbeta[17];
  uint32_t fk0[16];
  uint32_t fk1[16];
};

__host__ __device__ static inline void threefry2x32(uint32_t ks0, uint32_t ks1,
                                                    uint32_t x0, uint32_t x1,
                                                    uint32_t& o0, uint32_t& o1) {
  uint32_t ks2 = ks0 ^ ks1 ^ 0x1BD11BDAu;
  x0 += ks0; x1 += ks1;
#define TFR(r) { x0 += x1; x1 = (x1 << (r)) | (x1 >> (32 - (r))); x1 ^= x0; }
  TFR(13) TFR(15) TFR(26) TFR(6)
  x0 += ks1; x1 += ks2 + 1u;
  TFR(17) TFR(29) TFR(16) TFR(24)
  x0 += ks2; x1 += ks0 + 2u;
  TFR(13) TFR(15) TFR(26) TFR(6)
  x0 += ks0; x1 += ks1 + 3u;
  TFR(17) TFR(29) TFR(16) TFR(24)
  x0 += ks1; x1 += ks2 + 4u;
  TFR(13) TFR(15) TFR(26) TFR(6)
  x0 += ks2; x1 += ks0 + 5u;
#undef TFR
  o0 = x0; o1 = x1;
}

__device__ __forceinline__ float u_from_bits(uint32_t bits) {
  const float LO = __uint_as_float(0xBF7FFFFFu);  // nextafter(-1,0) in f32
  float f = __uint_as_float((bits >> 9) | 0x3F800000u) - 1.0f;
  return fmaf(f, 2.0f, LO);
}

// XLA ErfInv32 (Giles); __logf variant validated r11-r14 (absmax = 1 bf16 ulp)
__device__ __forceinline__ float erfinv_f(float x) {
  float w = -__logf(fmaf(-x, x, 1.0f));
  float p;
  if (w < 5.0f) {
    w -= 2.5f;
    p = 2.81022636e-08f;
    p = fmaf(p, w, 3.43273939e-07f);
    p = fmaf(p, w, -3.5233877e-06f);
    p = fmaf(p, w, -4.39150654e-06f);
    p = fmaf(p, w, 0.00021858087f);
    p = fmaf(p, w, -0.00125372503f);
    p = fmaf(p, w, -0.00417768164f);
    p = fmaf(p, w, 0.246640727f);
    p = fmaf(p, w, 1.50140941f);
  } else {
    w = sqrtf(w) - 3.0f;
    p = -0.000200214257f;
    p = fmaf(p, w, 0.000100950558f);
    p = fmaf(p, w, 0.00134934322f);
    p = fmaf(p, w, -0.00367342844f);
    p = fmaf(p, w, 0.00573950773f);
    p = fmaf(p, w, -0.0076224613f);
    p = fmaf(p, w, 0.00943887047f);
    p = fmaf(p, w, 1.00167406f);
    p = fmaf(p, w, 2.83297682f);
  }
  return p * x;
}

// ---- setup1: A = Wdec Wdec^T ; mu[b][d] ; c[b][d] ; xsq[b]
__global__ void k_setup1(const float* __restrict__ x, const float* __restrict__ Wenc,
                         const float* __restrict__ Wdec, float* __restrict__ ws) {
  int t = blockIdx.x * 256 + threadIdx.x;
  if (t < 4096) {
    int i = t >> 6, j = t & 63;
    float s = 0;
    for (int e = 0; e < 64; ++e) s = fmaf(Wdec[i*64+e], Wdec[j*64+e], s);
    ws[WS_A + t] = s;
  } else if (t < 12288) {
    int u = t - 4096; int b = u >> 6, d = u & 63;
    float s = 0;
    for (int e = 0; e < 64; ++e) s = fmaf(x[b*64+e], Wenc[e*64+d], s);
    ws[WS_MU + u] = s;
  } else if (t < 20480) {
    int u = t - 12288; int b = u >> 6, d = u & 63;
    float s = 0;
    for (int e = 0; e < 64; ++e) s = fmaf(x[b*64+e], Wdec[d*64+e], s);
    ws[WS_C + u] = s;
  } else if (t < 20608) {
    int b = t - 20480;
    float s = 0;
    for (int e = 0; e < 64; ++e) s = fmaf(x[b*64+e], x[b*64+e], s);
    ws[WS_XSQ + b] = s;
  }
}

#define DRAW(PC, IDX)                                                        \
  { uint32_t o0, o1;                                                         \
    threefry2x32(k0, k1, 0u, base + (IDX), o0, o1);                          \
    PC = 1.41421356f * erfinv_f(u_from_bits(o0 ^ o1)); }

#define PACKD(DST, DD)                                                       \
  { _Float16 hh = (_Float16)(DD);                                            \
    _Float16 ll = (_Float16)((DD) - (float)hh);                              \
    DST = (uint32_t)__builtin_bit_cast(unsigned short, hh) |                 \
          ((uint32_t)__builtin_bit_cast(unsigned short, ll) << 16); }

// ---- k_fused: block 0 = k_eig (3 sweeps); blocks 1..nRng = RNG producer;
// blocks nRng+1..nRng+8 = setup2. All roles independent (no inter-block deps).
#define EP 65
__global__ __launch_bounds__(1024) void k_fused(float* __restrict__ ws, KParams P,
                                                int nRng, int nS, int Lcut) {
  const int blk = blockIdx.x;
  const int tid = threadIdx.x;
  if (blk == 0) {
    // ---- cyclic Jacobi, 3 sweeps x 63 rounds, pitch 65 (r18 arithmetic)
    __shared__ float Am[64 * EP];
    __shared__ float Vm[64 * EP];
    __shared__ float cs_c[32], cs_s[32];
    __shared__ int ppu[32], ppv[32];
    for (int i = tid; i < 4096; i += 1024) {
      int r = i >> 6, c = i & 63;
      Am[r*EP + c] = ws[WS_A + i];
      Vm[r*EP + c] = (r == c) ? 1.0f : 0.0f;
    }
    const int pA = tid & 31;
    int uA = (pA == 0) ? 0 : pA;
    int vA = (pA == 0) ? 63 : (63 - pA);
    const int pV0 = tid >> 6;
    int uV0 = (pV0 == 0) ? 0 : pV0;
    int vV0 = (pV0 == 0) ? 63 : (63 - pV0);
    const int pV1 = 16 + pV0;
    int uV1 = pV1;
    int vV1 = 63 - pV1;
    __syncthreads();
    for (int sweep = 0; sweep < 3; ++sweep) {
      for (int r = 0; r < 63; ++r) {
        if (tid < 32) {
          float app = Am[uA*(EP+1)], aqq = Am[vA*(EP+1)], apq = Am[uA*EP+vA];
          float c = 1.0f, s = 0.0f;
          if (fabsf(apq) > 1e-30f) {
            float tau = (aqq - app) / (2.0f * apq);
            float t = copysignf(1.0f / (fabsf(tau) + sqrtf(fmaf(tau, tau, 1.0f))), tau);
            c = 1.0f / sqrtf(fmaf(t, t, 1.0f));
            s = t * c;
          }
          ppu[tid] = uA; ppv[tid] = vA; cs_c[tid] = c; cs_s[tid] = s;
        }
        __syncthreads();
        {
          int i = tid >> 5;
          int ui = ppu[i], vi = ppv[i];
          const int uj = uA, vj = vA;
          float ci = cs_c[i], si = cs_s[i], cj = cs_c[pA], sj = cs_s[pA];
          float a = Am[ui*EP+uj], bb = Am[ui*EP+vj];
          float d = Am[vi*EP+uj], e  = Am[vi*EP+vj];
          float r0u = ci*a  - si*d;
          float r1u = fmaf(si, a,  ci*d);
          float r0v = ci*bb - si*e;
          float r1v = fmaf(si, bb, ci*e);
          Am[ui*EP+uj] = cj*r0u - sj*r0v;
          Am[ui*EP+vj] = fmaf(sj, r0u, cj*r0v);
          Am[vi*EP+uj] = cj*r1u - sj*r1v;
          Am[vi*EP+vj] = fmaf(sj, r1u, cj*r1v);
        }
        {
          const int k = tid & 63;
          {
            float c2 = cs_c[pV0], s2 = cs_s[pV0];
            float vu = Vm[k*EP+uV0], vv = Vm[k*EP+vV0];
            Vm[k*EP+uV0] = c2*vu - s2*vv;
            Vm[k*EP+vV0] = fmaf(s2, vu, c2*vv);
          }
          {
            float c2 = cs_c[pV1], s2 = cs_s[pV1];
            float vu = Vm[k*EP+uV1], vv = Vm[k*EP+vV1];
            Vm[k*EP+uV1] = c2*vu - s2*vv;
            Vm[k*EP+vV1] = fmaf(s2, vu, c2*vv);
          }
        }
        uA  = (uA  == 0) ? 0 : ((uA  == 63) ? 1 : uA  + 1);
        vA  = (vA  == 63) ? 1 : vA  + 1;
        uV0 = (uV0 == 0) ? 0 : ((uV0 == 63) ? 1 : uV0 + 1);
        vV0 = (vV0 == 63) ? 1 : vV0 + 1;
        uV1 = (uV1 == 63) ? 1 : uV1 + 1;
        vV1 = (vV1 == 63) ? 1 : vV1 + 1;
        __syncthreads();
      }
    }
    for (int i = tid; i < 4096; i += 1024) ws[WS_V + i] = Vm[(i >> 6)*EP + (i & 63)];
    if (tid < 64) ws[WS_LAM + tid] = Am[tid*(EP+1)];
  } else if (blk <= nRng) {
    // ---- RNG producer: exact k_main DRAW+SPLIT, packed f16hi|f16lo u32,
    // step-major layout. Threads L < Lcut stage one extra (fractional) step.
    const int L = (blk - 1) * 1024 + tid;
    const int bI = L >> 8, t256 = L & 255;
    const int wv = t256 >> 6, lane = t256 & 63;
    const int cw = lane & 15, g4 = lane >> 4;
    const int koff = g4 * 8;
    const int trajBase = bI * 64 + wv * 16;
    const uint32_t base = (uint32_t)(trajBase + cw) * 64u;
    uint32_t* wsu = (uint32_t*)ws;
    const int nSteps = nS + ((nS < 16 && L < Lcut) ? 1 : 0);
    for (int j = 1; j <= nSteps; ++j) {
      const uint32_t k0 = P.fk0[j-1], k1 = P.fk1[j-1];
      uint32_t ov[16];
#pragma unroll
      for (int i = 0; i < 8; ++i) { float dd; DRAW(dd, koff + i) PACKD(ov[i], dd) }
#pragma unroll
      for (int i = 0; i < 8; ++i) { float dd; DRAW(dd, 32 + koff + i) PACKD(ov[8+i], dd) }
      uint4_t* wr = (uint4_t*)(wsu + WS_RNG + (size_t)(j-1)*STEP_U32 + (size_t)L*16u);
      wr[0] = (uint4_t){ov[0], ov[1], ov[2], ov[3]};
      wr[1] = (uint4_t){ov[4], ov[5], ov[6], ov[7]};
      wr[2] = (uint4_t){ov[8], ov[9], ov[10], ov[11]};
      wr[3] = (uint4_t){ov[12], ov[13], ov[14], ov[15]};
    }
  } else {
    // ---- setup2: amu[b][d] = (mu A)[d] ; f[b][d] = c - mu - amu
    int t = (blk - 1 - nRng) * 1024 + tid;
    if (t < 8192) {
      int b = t >> 6, d = t & 63;
      float s = 0;
      for (int m = 0; m < 64; ++m) s = fmaf(ws[WS_MU + b*64+m], ws[WS_A + m*64+d], s);
      ws[WS_AMU + t] = s;
      ws[WS_F + t] = ws[WS_C + t] - ws[WS_MU + t] - s;
    }
  }
}

// ---- setupfv (fz + VF + wconst): blocks 0-31: fz = f V; blocks 32-35: pack V
// into f16 hi/lo MFMA B-fragments; block 36: wconst[b].
__global__ void k_setupfv(float* __restrict__ ws) {
  int blk = blockIdx.x;
  if (blk < 32) {
    int t = blk * 256 + threadIdx.x;
    int b = t >> 6, d = t & 63;
    float s = 0;
    for (int m = 0; m < 64; ++m) s = fmaf(ws[WS_F + b*64+m], ws[WS_V + m*64+d], s);
    ws[WS_FZ + t] = s;
  } else if (blk < 36) {
    int idx = (blk - 32) * 256 + threadIdx.x;   // 0..1023
    int lane = idx & 63, F = idx >> 6;
    int t = F >> 3, kt = (F >> 2) & 1, nt = F & 3;
    int n = nt*16 + (lane & 15);
    int k0 = kt*32 + ((lane >> 4) & 3)*8;
    uint32_t out[4];
    for (int jj = 0; jj < 4; ++jj) {
      float v0 = ws[WS_V + (k0 + 2*jj    )*64 + n];
      float v1 = ws[WS_V + (k0 + 2*jj + 1)*64 + n];
      _Float16 h0, h1;
      if (t == 0) { h0 = (_Float16)v0; h1 = (_Float16)v1; }
      else {
        _Float16 a0 = (_Float16)v0, a1 = (_Float16)v1;
        h0 = (_Float16)(v0 - (float)a0);
        h1 = (_Float16)(v1 - (float)a1);
      }
      unsigned short u0 = __builtin_bit_cast(unsigned short, h0);
      unsigned short u1 = __builtin_bit_cast(unsigned short, h1);
      out[jj] = (uint32_t)u0 | ((uint32_t)u1 << 16);
    }
    uint32_t* dst = (uint32_t*)ws + WS_VF + idx*4;
    dst[0] = out[0]; dst[1] = out[1]; dst[2] = out[2]; dst[3] = out[3];
  } else {
    int b = threadIdx.x;
    if (b < 128) {
      float muc = 0, musq = 0, muamu = 0;
      for (int d = 0; d < 64; ++d) {
        float m = ws[WS_MU + b*64+d];
        muc   = fmaf(m, ws[WS_C + b*64+d], muc);
        musq  = fmaf(m, m, musq);
        muamu = fmaf(m, ws[WS_AMU + b*64+d], muamu);
      }
      ws[WS_WC + b] = -32.0f * LOG2PI - 0.5f * ws[WS_XSQ + b]
                      + muc - 0.5f * musq - 0.5f * muamu;
    }
  }
}

// ---- k_main hot-loop macros ------------------------------------------------

#define SPLIT1(AH, AL, J, VV)                                                \
  { _Float16 hh = (_Float16)(VV); AH[J] = hh;                                \
    AL[J] = (_Float16)((VV) - (float)hh); }

#define DRAWSPLIT8(AH, AL, KB)                                               \
  { float dd;                                                                \
    DRAW(dd, (KB)+0) SPLIT1(AH, AL, 0, dd)                                   \
    DRAW(dd, (KB)+1) SPLIT1(AH, AL, 1, dd)                                   \
    DRAW(dd, (KB)+2) SPLIT1(AH, AL, 2, dd)                                   \
    DRAW(dd, (KB)+3) SPLIT1(AH, AL, 3, dd)                                   \
    DRAW(dd, (KB)+4) SPLIT1(AH, AL, 4, dd)                                   \
    DRAW(dd, (KB)+5) SPLIT1(AH, AL, 5, dd)                                   \
    DRAW(dd, (KB)+6) SPLIT1(AH, AL, 6, dd)                                   \
    DRAW(dd, (KB)+7) SPLIT1(AH, AL, 7, dd) }

#define FRAGB(T, KT, NT)                                                     \
  __builtin_bit_cast(half8_t, VF[(((T)*2+(KT))*4+(NT))*64 + lane])

#define ROT1(ZO, NT, AH0, AL0, AH1, AL1)                                     \
  { half8_t bh0 = FRAGB(0,0,NT), bh1 = FRAGB(0,1,NT);                        \
    half8_t bl0 = FRAGB(1,0,NT), bl1 = FRAGB(1,1,NT);                        \
    f4_t aa = {0.f, 0.f, 0.f, 0.f};                                          \
    aa = __builtin_amdgcn_mfma_f32_16x16x32_f16(AH0, bh0, aa, 0, 0, 0);      \
    aa = __builtin_amdgcn_mfma_f32_16x16x32_f16(AH1, bh1, aa, 0, 0, 0);      \
    aa = __builtin_amdgcn_mfma_f32_16x16x32_f16(AL0, bh0, aa, 0, 0, 0);      \
    aa = __builtin_amdgcn_mfma_f32_16x16x32_f16(AL1, bh1, aa, 0, 0, 0);      \
    aa = __builtin_amdgcn_mfma_f32_16x16x32_f16(AH0, bl0, aa, 0, 0, 0);      \
    aa = __builtin_amdgcn_mfma_f32_16x16x32_f16(AH1, bl1, aa, 0, 0, 0);      \
    ZO = aa; }

#define ROTATE4(O0, O1, O2, O3, AH0, AL0, AH1, AL1)                          \
  ROT1(O0, 0, AH0, AL0, AH1, AL1) ROT1(O1, 1, AH0, AL0, AH1, AL1)            \
  ROT1(O2, 2, AH0, AL0, AH1, AL1) ROT1(O3, 3, AH0, AL0, AH1, AL1)

// vectorized leapfrog: v_pk_fma_f32 path, IEEE-identical per component
#define LF4V(ZV, PV, NLM, FV, DBL)                                           \
  { f4_t gg = __builtin_elementwise_fma(bk4,                                 \
        __builtin_elementwise_fma(NLM, ZV, FV), -ZV);                        \
    PV = __builtin_elementwise_fma(c025v, gg, PV);                           \
    if (DBL) PV = __builtin_elementwise_fma(c025v, gg, PV);                  \
    ZV = __builtin_elementwise_fma(c005v, PV, ZV); }
#define SUBSTEPV(DBL)                                                        \
  LF4V(z0, pz0, nlm0, fzv0, DBL) LF4V(z1, pz1, nlm1, fzv1, DBL)              \
  LF4V(z2, pz2, nlm2, fzv2, DBL) LF4V(z3, pz3, nlm3, fzv3, DBL)

#define W_EVALN(WOUT)                                                        \
  { f4_t s1 = fzv0*z0 + fzv1*z1 + fzv2*z2 + fzv3*z3;                         \
    f4_t s2 = (lmS0*z0)*z0 + (lmS1*z1)*z1 + (lmS2*z2)*z2 + (lmS3*z3)*z3;     \
    f4_t vv = s1 - 0.5f*s2;                                                  \
    float r0 = vv.x, r1 = vv.y, r2 = vv.z, r3 = vv.w;                        \
    r0 += __shfl_xor(r0, 1); r1 += __shfl_xor(r1, 1);                        \
    r2 += __shfl_xor(r2, 1); r3 += __shfl_xor(r3, 1);                        \
    r0 += __shfl_xor(r0, 2); r1 += __shfl_xor(r1, 2);                        \
    r2 += __shfl_xor(r2, 2); r3 += __shfl_xor(r3, 2);                        \
    r0 += __shfl_xor(r0, 4); r1 += __shfl_xor(r1, 4);                        \
    r2 += __shfl_xor(r2, 4); r3 += __shfl_xor(r3, 4);                        \
    r0 += __shfl_xor(r0, 8); r1 += __shfl_xor(r1, 8);                        \
    r2 += __shfl_xor(r2, 8); r3 += __shfl_xor(r3, 8);                        \
    float wsel = (cw == 0) ? r0 : ((cw == 1) ? r1 : ((cw == 2) ? r2 : r3));  \
    WOUT = wsel + wcs; }

#define PLO 0x05040100u
#define PHI 0x07060302u

// ---- main: MFMA rotation; wave = 16 trajs; 4 waves/block, 2048 blocks.
__global__ __launch_bounds__(256) void k_main(const float* __restrict__ qn,
                                              const float* __restrict__ ws,
                                              float* __restrict__ slw_out,
                                              KParams P, int nS, int Lcut) {
  __shared__ uint4_t VF[1024];   // 16 KB: V f16 hi/lo B-fragments
  const int tid = threadIdx.x;
  {
    const uint4_t* src = (const uint4_t*)((const uint32_t*)ws + WS_VF);
    for (int i = tid; i < 1024; i += 256) VF[i] = src[i];
  }
  __syncthreads();

  const int lane = tid & 63;
  const int wv = tid >> 6;
  const int cw = lane & 15;              // MFMA col; also A-operand row m
  const int g4 = lane >> 4;              // quad id
  const int koff = g4 * 8;               // A-fragment k offset
  const int trajBase = blockIdx.x * 64 + wv * 16;
  const uint32_t base = (uint32_t)(trajBase + cw) * 64u;   // RNG row base
  const int Lme = blockIdx.x * 256 + tid;                  // staged-RNG row

  const int b0 = (trajBase + g4*4 + 0) & 127;
  const int b1 = (trajBase + g4*4 + 1) & 127;
  const int b2 = (trajBase + g4*4 + 2) & 127;
  const int b3 = (trajBase + g4*4 + 3) & 127;
  f4_t fzv0, fzv1, fzv2, fzv3;
  fzv0.x = ws[WS_FZ + b0*64 + cw];      fzv0.y = ws[WS_FZ + b1*64 + cw];
  fzv0.z = ws[WS_FZ + b2*64 + cw];      fzv0.w = ws[WS_FZ + b3*64 + cw];
  fzv1.x = ws[WS_FZ + b0*64 + 16 + cw]; fzv1.y = ws[WS_FZ + b1*64 + 16 + cw];
  fzv1.z = ws[WS_FZ + b2*64 + 16 + cw]; fzv1.w = ws[WS_FZ + b3*64 + 16 + cw];
  fzv2.x = ws[WS_FZ + b0*64 + 32 + cw]; fzv2.y = ws[WS_FZ + b1*64 + 32 + cw];
  fzv2.z = ws[WS_FZ + b2*64 + 32 + cw]; fzv2.w = ws[WS_FZ + b3*64 + 32 + cw];
  fzv3.x = ws[WS_FZ + b0*64 + 48 + cw]; fzv3.y = ws[WS_FZ + b1*64 + 48 + cw];
  fzv3.z = ws[WS_FZ + b2*64 + 48 + cw]; fzv3.w = ws[WS_FZ + b3*64 + 48 + cw];
  const float lmS0 = ws[WS_LAM + cw];
  const float lmS1 = ws[WS_LAM + 16 + cw];
  const float lmS2 = ws[WS_LAM + 32 + cw];
  const float lmS3 = ws[WS_LAM + 48 + cw];
  const float wcs = ws[WS_WC + ((trajBase + g4*4 + (cw & 3)) & 127)];
  const f4_t nlm0 = {-lmS0, -lmS0, -lmS0, -lmS0};
  const f4_t nlm1 = {-lmS1, -lmS1, -lmS1, -lmS1};
  const f4_t nlm2 = {-lmS2, -lmS2, -lmS2, -lmS2};
  const f4_t nlm3 = {-lmS3, -lmS3, -lmS3, -lmS3};
  const f4_t c025v = {0.025f, 0.025f, 0.025f, 0.025f};
  const f4_t c005v = {0.05f, 0.05f, 0.05f, 0.05f};

  f4_t z0, z1, z2, z3, pz0, pz1, pz2, pz3;
  float slw = 0.0f;

  // j = 0: z0 = qn . V  (qn read at A-fragment positions; f16 3-term split)
  {
    const float* qp = qn + (size_t)base;
    f4_t qa = *(const f4_t*)(qp + koff);
    f4_t qb = *(const f4_t*)(qp + koff + 4);
    f4_t qc = *(const f4_t*)(qp + 32 + koff);
    f4_t qd = *(const f4_t*)(qp + 32 + koff + 4);
    half8_t ah0, al0, ah1, al1;
    SPLIT1(ah0, al0, 0, qa.x) SPLIT1(ah0, al0, 1, qa.y)
    SPLIT1(ah0, al0, 2, qa.z) SPLIT1(ah0, al0, 3, qa.w)
    SPLIT1(ah0, al0, 4, qb.x) SPLIT1(ah0, al0, 5, qb.y)
    SPLIT1(ah0, al0, 6, qb.z) SPLIT1(ah0, al0, 7, qb.w)
    SPLIT1(ah1, al1, 0, qc.x) SPLIT1(ah1, al1, 1, qc.y)
    SPLIT1(ah1, al1, 2, qc.z) SPLIT1(ah1, al1, 3, qc.w)
    SPLIT1(ah1, al1, 4, qd.x) SPLIT1(ah1, al1, 5, qd.y)
    SPLIT1(ah1, al1, 6, qd.z) SPLIT1(ah1, al1, 7, qd.w)
    ROTATE4(z0, z1, z2, z3, ah0, al0, ah1, al1)
  }
  {
    float w0;
    W_EVALN(w0);
    slw = fmaf(P.dbeta[0], w0, slw);
  }

  for (int j = 1; j <= 16; ++j) {
    const float bk = P.beta[j];
    const f4_t bk4 = {bk, bk, bk, bk};
    half8_t ah0, al0, ah1, al1;
    if (j <= nS || (j == nS + 1 && Lme < Lcut)) {
      // staged: load packed f16hi|f16lo draws (step-major), unpack via v_perm
      const uint32_t* rp = (const uint32_t*)ws + WS_RNG
                         + (size_t)(j-1)*STEP_U32 + (size_t)Lme*16u;
      const uint4_t* rr = (const uint4_t*)rp;
      uint4_t q0 = rr[0], q1 = rr[1], q2 = rr[2], q3 = rr[3];
      uint4_t uh0 = { __builtin_amdgcn_perm(q0.y, q0.x, PLO),
                      __builtin_amdgcn_perm(q0.w, q0.z, PLO),
                      __builtin_amdgcn_perm(q1.y, q1.x, PLO),
                      __builtin_amdgcn_perm(q1.w, q1.z, PLO) };
      uint4_t ul0 = { __builtin_amdgcn_perm(q0.y, q0.x, PHI),
                      __builtin_amdgcn_perm(q0.w, q0.z, PHI),
                      __builtin_amdgcn_perm(q1.y, q1.x, PHI),
                      __builtin_amdgcn_perm(q1.w, q1.z, PHI) };
      uint4_t uh1 = { __builtin_amdgcn_perm(q2.y, q2.x, PLO),
                      __builtin_amdgcn_perm(q2.w, q2.z, PLO),
                      __builtin_amdgcn_perm(q3.y, q3.x, PLO),
                      __builtin_amdgcn_perm(q3.w, q3.z, PLO) };
      uint4_t ul1 = { __builtin_amdgcn_perm(q2.y, q2.x, PHI),
                      __builtin_amdgcn_perm(q2.w, q2.z, PHI),
                      __builtin_amdgcn_perm(q3.y, q3.x, PHI),
                      __builtin_amdgcn_perm(q3.w, q3.z, PHI) };
      ah0 = __builtin_bit_cast(half8_t, uh0);
      al0 = __builtin_bit_cast(half8_t, ul0);
      ah1 = __builtin_bit_cast(half8_t, uh1);
      al1 = __builtin_bit_cast(half8_t, ul1);
    } else {
      const uint32_t k0 = P.fk0[j-1], k1 = P.fk1[j-1];
      DRAWSPLIT8(ah0, al0, koff)
      DRAWSPLIT8(ah1, al1, 32 + koff)
    }
    ROTATE4(pz0, pz1, pz2, pz3, ah0, al0, ah1, al1)   // pz = p . V
    SUBSTEPV(false)
    SUBSTEPV(true)
    SUBSTEPV(true)
    float wj;
    W_EVALN(wj);
    slw = fmaf(P.dbeta[j], wj, slw);
  }
  if (cw < 4) slw_out[trajBase + g4*4 + cw] = slw;
}

// ---- logsumexp over n per batch column b
__global__ void k_reduce(const float* __restrict__ slw, float* __restrict__ out) {
  __shared__ float red[256];
  int b = blockIdx.x, t = threadIdx.x;
  float v0 = slw[t*128 + b];
  float v1 = slw[(t+256)*128 + b];
  float v2 = slw[(t+512)*128 + b];
  float v3 = slw[(t+768)*128 + b];
  float m = fmaxf(fmaxf(v0, v1), fmaxf(v2, v3));
  red[t] = m; __syncthreads();
  for (int s = 128; s > 0; s >>= 1) {
    if (t < s) red[t] = fmaxf(red[t], red[t+s]);
    __syncthreads();
  }
  m = red[0]; __syncthreads();
  float sum = expf(v0 - m) + expf(v1 - m) + expf(v2 - m) + expf(v3 - m);
  red[t] = sum; __syncthreads();
  for (int s = 128; s > 0; s >>= 1) {
    if (t < s) red[t] += red[t+s];
    __syncthreads();
  }
  if (t == 0) out[b] = m + logf(red[0]) - 6.93147180559945309f;  // - log(1024)
}

extern "C" void kernel_launch(void* const* d_in, const int* in_sizes, int n_in,
                              void* d_out, int out_size, void* d_ws, size_t ws_size,
                              hipStream_t stream) {
  const float* x    = (const float*)d_in[0];
  const float* Wenc = (const float*)d_in[1];
  const float* Wdec = (const float*)d_in[2];
  const float* qn   = (const float*)d_in[3];
  // d_in[4] (p_noise) is dead: momentum fully resampled every anneal step.
  float* ws  = (float*)d_ws;
  float* out = (float*)d_out;
  if (ws_size < (size_t)WS_TOTAL * sizeof(float)) return;

  // staged-RNG step count from available workspace (33.55 MB per step),
  // plus fractional staging of the next step with the leftover.
  size_t avail_u32 = ws_size / 4;
  int nS = 0, Lcut = 0;
  if (avail_u32 > (size_t)WS_RNG) {
    size_t r = avail_u32 - (size_t)WS_RNG;
    nS = (int)(r / STEP_U32);
    if (nS > 16) nS = 16;
    if (nS < 16) {
      size_t rem = r - (size_t)nS * STEP_U32;
      size_t lc = (rem / 16) & ~(size_t)63;       // wave-aligned thread count
      if (lc > 524288) lc = 524288;
      Lcut = (int)lc;
    }
  }
  const int nRng = (nS > 0 || Lcut > 0) ? 512 : 0;

  KParams P;
  double bb[18];
  for (int i = 0; i < 18; ++i) {
    double tt = (double)i / 17.0;
    bb[i] = 1.0 / (1.0 + exp(-(8.0 * tt - 4.0)));
  }
  for (int i = 0; i < 18; ++i) P.beta[i] = (float)((bb[i] - bb[0]) / (bb[17] - bb[0]));
  for (int j = 0; j <= 16; ++j) P.dbeta[j] = P.beta[j+1] - P.beta[j];
  for (int k = 1; k <= 16; ++k) {
    uint32_t a, c;
    threefry2x32(0u, 42u, 0u, (uint32_t)k, a, c);  // fold_in(key(42), k)
    P.fk0[k-1] = a; P.fk1[k-1] = c;
  }

  hipLaunchKernelGGL(k_setup1, dim3(81), dim3(256), 0, stream, x, Wenc, Wdec, ws);
  hipLaunchKernelGGL(k_fused, dim3(1 + nRng + 8), dim3(1024), 0, stream, ws, P, nRng, nS, Lcut);
  hipLaunchKernelGGL(k_setupfv, dim3(37), dim3(256), 0, stream, ws);
  hipLaunchKernelGGL(k_main, dim3(2048), dim3(256), 0, stream, qn, ws, ws + WS_SLW, P, nS, Lcut);
  hipLaunchKernelGGL(k_reduce, dim3(128), dim3(256), 0, stream, ws + WS_SLW, out);
}